// Round 1
// baseline (4359.704 us; speedup 1.0000x reference)
//
#include <hip/hip_runtime.h>
#include <stdint.h>

#define D_VIT 768
#define D_SAE 12288
#define TOPK 32
#define NCAND 48
#define SLOTS 48   // D_SAE / 256

// ---------------- transpose W_enc (768 x 12288) -> wt (12288 x 768) ----------
__global__ void k_transpose(const float* __restrict__ src, float* __restrict__ dst) {
    __shared__ float t[32][33];
    int bx = blockIdx.x;  // over D_SAE/32
    int by = blockIdx.y;  // over D_VIT/32
    int tx = threadIdx.x; // 0..31
    int ty = threadIdx.y; // 0..7
    int f0 = bx * 32, k0 = by * 32;
#pragma unroll
    for (int j = 0; j < 32; j += 8)
        t[ty + j][tx] = src[(size_t)(k0 + ty + j) * D_SAE + f0 + tx];
    __syncthreads();
#pragma unroll
    for (int j = 0; j < 32; j += 8)
        dst[(size_t)(f0 + ty + j) * D_VIT + k0 + tx] = t[tx][ty + j];
}

// ---------------- encoder GEMM: acts = relu((x - b_dec) @ W_enc) -------------
#define BM 128
#define BN 128
#define BK 8
#define TM 8
#define TN 8

__global__ __launch_bounds__(256) void k_encoder(
    const float* __restrict__ x, const float* __restrict__ wenc,
    const float* __restrict__ bdec, float* __restrict__ acts,
    int row0, int mrows) {
    __shared__ float As[BK][BM];
    __shared__ float Bs[BK][BN];
    int bn = blockIdx.x;  // 0..D_SAE/BN-1
    int bm = blockIdx.y;  // row tile
    int tid = threadIdx.x;
    int tx = tid & 15, ty = tid >> 4;
    int m_base = bm * BM, n_base = bn * BN;
    float acc[TM][TN] = {};

    int ar = tid >> 1, ah = tid & 1;   // A loader: row, half
    int bk = tid >> 5, bq = tid & 31;  // B loader: k-row, quad

    for (int k0 = 0; k0 < D_VIT; k0 += BK) {
        float4 av = make_float4(0.f, 0.f, 0.f, 0.f);
        int rr = m_base + ar;
        if (rr < mrows) {
            av = *reinterpret_cast<const float4*>(&x[(size_t)(row0 + rr) * D_VIT + k0 + ah * 4]);
            float4 bv = *reinterpret_cast<const float4*>(&bdec[k0 + ah * 4]);
            av.x -= bv.x; av.y -= bv.y; av.z -= bv.z; av.w -= bv.w;
        }
        As[ah * 4 + 0][ar] = av.x;
        As[ah * 4 + 1][ar] = av.y;
        As[ah * 4 + 2][ar] = av.z;
        As[ah * 4 + 3][ar] = av.w;
        float4 wv = *reinterpret_cast<const float4*>(&wenc[(size_t)(k0 + bk) * D_SAE + n_base + bq * 4]);
        *reinterpret_cast<float4*>(&Bs[bk][bq * 4]) = wv;
        __syncthreads();
#pragma unroll
        for (int kk = 0; kk < BK; ++kk) {
            float a[TM], b[TN];
#pragma unroll
            for (int i = 0; i < TM; i++) a[i] = As[kk][ty * TM + i];
#pragma unroll
            for (int j = 0; j < TN; j++) b[j] = Bs[kk][tx * TN + j];
#pragma unroll
            for (int i = 0; i < TM; i++)
#pragma unroll
                for (int j = 0; j < TN; j++) acc[i][j] = fmaf(a[i], b[j], acc[i][j]);
        }
        __syncthreads();
    }
#pragma unroll
    for (int i = 0; i < TM; i++) {
        int r = m_base + ty * TM + i;
        if (r < mrows) {
            float4 o0, o1;
            o0.x = fmaxf(acc[i][0], 0.f); o0.y = fmaxf(acc[i][1], 0.f);
            o0.z = fmaxf(acc[i][2], 0.f); o0.w = fmaxf(acc[i][3], 0.f);
            o1.x = fmaxf(acc[i][4], 0.f); o1.y = fmaxf(acc[i][5], 0.f);
            o1.z = fmaxf(acc[i][6], 0.f); o1.w = fmaxf(acc[i][7], 0.f);
            float* p = &acts[(size_t)r * D_SAE + n_base + tx * TN];
            *reinterpret_cast<float4*>(p) = o0;
            *reinterpret_cast<float4*>(p + 4) = o1;
        }
    }
}

// ---------------- per-row: top-48 select, f64 rerank, top-32, decode ---------
__global__ __launch_bounds__(256) void k_select(
    const float* __restrict__ acts, const float* __restrict__ x,
    const float* __restrict__ bdec, const float* __restrict__ wt,
    const float* __restrict__ wdec, float* __restrict__ out,
    int row0, int mrows, int do_rerank) {
    int lrow = blockIdx.x;
    int row = row0 + lrow;
    int tid = threadIdx.x;

    __shared__ float xs[D_VIT];
    __shared__ int cand_f[NCAND];
    __shared__ double cval[NCAND];
    __shared__ unsigned long long red[4];
    __shared__ int sidx[TOPK];
    __shared__ float sval[TOPK];

    for (int i = tid; i < D_VIT; i += 256) xs[i] = x[(size_t)row * D_VIT + i] - bdec[i];

    float v[SLOTS];
#pragma unroll
    for (int i = 0; i < SLOTS; i++) v[i] = acts[(size_t)lrow * D_SAE + tid + 256 * i];

    unsigned long long dead = 0ull;
    for (int it = 0; it < NCAND; ++it) {
        float best = -1.0f; int bslot = 0;
#pragma unroll
        for (int i = 0; i < SLOTS; i++) {
            float xv = ((dead >> i) & 1ull) ? -1.0f : v[i];
            if (xv > best) { best = xv; bslot = i; }
        }
        unsigned int fb = best >= 0.0f ? __float_as_uint(best) : 0u;
        unsigned int fl = (unsigned int)(bslot * 256 + tid);
        unsigned long long p = ((unsigned long long)fb << 32) | (unsigned long long)(0xFFFFFFFFu - fl);
#pragma unroll
        for (int o = 1; o < 64; o <<= 1) {
            unsigned long long q = __shfl_xor(p, o);
            p = p > q ? p : q;
        }
        if ((tid & 63) == 0) red[tid >> 6] = p;
        __syncthreads();
        unsigned long long pm = red[0];
        if (red[1] > pm) pm = red[1];
        if (red[2] > pm) pm = red[2];
        if (red[3] > pm) pm = red[3];
        unsigned int f = 0xFFFFFFFFu - (unsigned int)(pm & 0xFFFFFFFFull);
        if (tid == (int)(f & 255u)) dead |= (1ull << (f >> 8));
        if (tid == 0) {
            cand_f[it] = (int)f;
            cval[it] = (double)__uint_as_float((unsigned int)(pm >> 32));
        }
        __syncthreads();
    }

    if (do_rerank) {
        int c = tid >> 2, sub = tid & 3;
        double acc = 0.0;
        if (c < NCAND) {
            const float* wr = &wt[(size_t)cand_f[c] * D_VIT];
            for (int k = sub; k < D_VIT; k += 4)
                acc += (double)xs[k] * (double)wr[k];
        }
        acc += __shfl_xor(acc, 1);
        acc += __shfl_xor(acc, 2);
        if (c < NCAND && sub == 0) cval[c] = acc > 0.0 ? acc : 0.0;
        __syncthreads();
    }

    if (tid < 64) {
        double myv = tid < NCAND ? cval[tid] : -1.0;
        for (int it = 0; it < TOPK; ++it) {
            double m = myv;
#pragma unroll
            for (int o = 1; o < 64; o <<= 1) {
                double q = __shfl_xor(m, o);
                m = q > m ? q : m;
            }
            unsigned long long b = __ballot(myv == m);
            int src = __ffsll((unsigned long long)b) - 1;
            if (tid == src) myv = -1.0;
            if (tid == 0) { sidx[it] = cand_f[src]; sval[it] = (float)m; }
        }
    }
    __syncthreads();

    for (int d = tid; d < D_VIT; d += 256) {
        float o = bdec[d];
#pragma unroll
        for (int j = 0; j < TOPK; j++)
            o = fmaf(sval[j], wdec[(size_t)sidx[j] * D_VIT + d], o);
        out[(size_t)row * D_VIT + d] = o;
    }
}

extern "C" void kernel_launch(void* const* d_in, const int* in_sizes, int n_in,
                              void* d_out, int out_size, void* d_ws, size_t ws_size,
                              hipStream_t stream) {
    const float* x    = (const float*)d_in[0];
    const float* wenc = (const float*)d_in[1];
    const float* wdec = (const float*)d_in[2];
    const float* bdec = (const float*)d_in[3];
    float* out = (float*)d_out;
    int M = in_sizes[0] / D_VIT;

    size_t wt_bytes  = (size_t)D_SAE * D_VIT * sizeof(float);
    size_t row_bytes = (size_t)D_SAE * sizeof(float);
    int do_rerank = ws_size >= wt_bytes + row_bytes ? 1 : 0;
    float* wt     = (float*)d_ws;
    float* actbuf = do_rerank ? (float*)((char*)d_ws + wt_bytes) : (float*)d_ws;
    size_t avail = ws_size - (do_rerank ? wt_bytes : 0);
    long long chl = (long long)(avail / row_bytes);
    int CH = (int)(chl < 1 ? 1 : (chl > (long long)M ? M : chl));

    if (do_rerank) {
        dim3 g(D_SAE / 32, D_VIT / 32), b(32, 8);
        hipLaunchKernelGGL(k_transpose, g, b, 0, stream, wenc, wt);
    }
    for (int s = 0; s < M; s += CH) {
        int mr = (M - s) < CH ? (M - s) : CH;
        dim3 ge(D_SAE / BN, (mr + BM - 1) / BM), be(256);
        hipLaunchKernelGGL(k_encoder, ge, be, 0, stream, x, wenc, bdec, actbuf, s, mr);
        hipLaunchKernelGGL(k_select, dim3(mr), dim3(256), 0, stream,
                           actbuf, x, bdec, wt, wdec, out, s, mr, do_rerank);
    }
}

// Round 2
// 2155.106 us; speedup vs baseline: 2.0230x; 2.0230x over previous
//
#include <hip/hip_runtime.h>
#include <hip/hip_bf16.h>
#include <stdint.h>

#define D_VIT 768
#define D_SAE 12288
#define TOPK 32
#define NCAND 48
#define SLOTS 48   // D_SAE / 256

typedef __attribute__((ext_vector_type(8))) short bf8_t;   // 8 bf16 (4 VGPRs)
typedef __attribute__((ext_vector_type(4))) float f4_t;    // 4 f32 acc
typedef const __attribute__((address_space(1))) void* gas_t;
typedef __attribute__((address_space(3))) void* las_t;

// ---------------- transpose W_enc (768 x 12288) -> wt f32 + wtb bf16 ---------
__global__ void k_transpose(const float* __restrict__ src, float* __restrict__ dst,
                            __hip_bfloat16* __restrict__ dstb) {
    __shared__ float t[32][33];
    int f0 = blockIdx.x * 32, k0 = blockIdx.y * 32;
    int tx = threadIdx.x, ty = threadIdx.y;
#pragma unroll
    for (int j = 0; j < 32; j += 8)
        t[ty + j][tx] = src[(size_t)(k0 + ty + j) * D_SAE + f0 + tx];
    __syncthreads();
#pragma unroll
    for (int j = 0; j < 32; j += 8) {
        float v = t[tx][ty + j];
        dst[(size_t)(f0 + ty + j) * D_VIT + k0 + tx] = v;
        dstb[(size_t)(f0 + ty + j) * D_VIT + k0 + tx] = __float2bfloat16(v);
    }
}

// ---------------- xb = bf16(x - b_dec) ---------------------------------------
__global__ __launch_bounds__(256) void k_cvt_x(const float* __restrict__ x,
    const float* __restrict__ bdec, __hip_bfloat16* __restrict__ xb, long long n) {
    long long i = ((long long)blockIdx.x * 256 + threadIdx.x) * 8;
    if (i >= n) return;
    float4 a = *reinterpret_cast<const float4*>(x + i);
    float4 b = *reinterpret_cast<const float4*>(x + i + 4);
    int kk = (int)(i % D_VIT);
    float4 c = *reinterpret_cast<const float4*>(bdec + kk);
    float4 d = *reinterpret_cast<const float4*>(bdec + kk + 4);
    union { __hip_bfloat16 h[8]; uint4 v; } o;
    o.h[0] = __float2bfloat16(a.x - c.x); o.h[1] = __float2bfloat16(a.y - c.y);
    o.h[2] = __float2bfloat16(a.z - c.z); o.h[3] = __float2bfloat16(a.w - c.w);
    o.h[4] = __float2bfloat16(b.x - d.x); o.h[5] = __float2bfloat16(b.y - d.y);
    o.h[6] = __float2bfloat16(b.z - d.z); o.h[7] = __float2bfloat16(b.w - d.w);
    *reinterpret_cast<uint4*>(xb + i) = o.v;
}

// ---------------- MFMA encoder: acts = relu(xb @ wtb^T) ----------------------
// A = xb [M][768] bf16 row-major; B = wtb [12288][768] bf16 row-major (= W_enc^T)
#define EBM 128
#define EBN 128
#define EBK 64

__global__ __launch_bounds__(256) void k_enc_mfma(
    const __hip_bfloat16* __restrict__ xb, const __hip_bfloat16* __restrict__ wtb,
    float* __restrict__ acts, int row0, int mrows, int Mtot) {
    __shared__ __hip_bfloat16 As[EBM * EBK];
    __shared__ __hip_bfloat16 Bs[EBN * EBK];
    int tid = threadIdx.x;
    int lane = tid & 63, w = tid >> 6;
    int wm = w >> 1, wn = w & 1;
    int tile_m = blockIdx.y * EBM, tile_n = blockIdx.x * EBN;

    f4_t acc[4][4] = {};

#pragma unroll 1
    for (int k0 = 0; k0 < D_VIT; k0 += EBK) {
        // stage: 1024 granules of 16B per tile; granule G = w*64 + j*256 + lane
        // LDS (row r, slot g) holds global k-granule (g ^ (r&7))  [rule #21]
#pragma unroll
        for (int j = 0; j < 4; ++j) {
            int G = w * 64 + j * 256 + lane;
            int r = G >> 3, g = G & 7;
            int gg = g ^ (r & 7);
            int ar = row0 + tile_m + r; if (ar >= Mtot) ar = Mtot - 1;
            const __hip_bfloat16* ga = xb + (size_t)ar * D_VIT + k0 + gg * 8;
            __builtin_amdgcn_global_load_lds((gas_t)ga,
                (las_t)(As + (w * 64 + j * 256) * 8), 16, 0, 0);
            const __hip_bfloat16* gb = wtb + (size_t)(tile_n + r) * D_VIT + k0 + gg * 8;
            __builtin_amdgcn_global_load_lds((gas_t)gb,
                (las_t)(Bs + (w * 64 + j * 256) * 8), 16, 0, 0);
        }
        __syncthreads();

        int lrow = lane & 15, lk = lane >> 4;  // fragment row, k-quarter
#pragma unroll
        for (int half = 0; half < 2; ++half) {
            int g = lk + half * 4;             // k-granule 0..7
            bf8_t af[4], bfr[4];
#pragma unroll
            for (int f = 0; f < 4; ++f) {
                int r = wm * 64 + f * 16 + lrow;
                af[f] = *reinterpret_cast<const bf8_t*>(As + r * EBK + ((g ^ (lrow & 7)) << 3));
                int rn = wn * 64 + f * 16 + lrow;
                bfr[f] = *reinterpret_cast<const bf8_t*>(Bs + rn * EBK + ((g ^ (lrow & 7)) << 3));
            }
#pragma unroll
            for (int i = 0; i < 4; ++i)
#pragma unroll
                for (int jn = 0; jn < 4; ++jn)
                    acc[i][jn] = __builtin_amdgcn_mfma_f32_16x16x32_bf16(
                        af[i], bfr[jn], acc[i][jn], 0, 0, 0);
        }
        __syncthreads();
    }

    // C-write with fused relu; C/D layout: col = lane&15, row = (lane>>4)*4 + q
#pragma unroll
    for (int i = 0; i < 4; ++i) {
        int rbase = tile_m + wm * 64 + i * 16 + (lane >> 4) * 4;
#pragma unroll
        for (int jn = 0; jn < 4; ++jn) {
            int c = tile_n + wn * 64 + jn * 16 + (lane & 15);
#pragma unroll
            for (int q = 0; q < 4; ++q) {
                int rr = rbase + q;
                if (rr < mrows) acts[(size_t)rr * D_SAE + c] = fmaxf(acc[i][jn][q], 0.f);
            }
        }
    }
}

// ---------------- per-row: top-48 select, f64 rerank, top-32, decode ---------
__global__ __launch_bounds__(256) void k_select(
    const float* __restrict__ acts, const float* __restrict__ x,
    const float* __restrict__ bdec, const float* __restrict__ wt,
    const float* __restrict__ wdec, float* __restrict__ out,
    int row0, int mrows) {
    int lrow = blockIdx.x;
    int row = row0 + lrow;
    int tid = threadIdx.x;

    __shared__ float xs[D_VIT];
    __shared__ int cand_f[NCAND];
    __shared__ double cval[NCAND];
    __shared__ unsigned long long red[4];
    __shared__ int sidx[TOPK];
    __shared__ float sval[TOPK];

    for (int i = tid; i < D_VIT; i += 256) xs[i] = x[(size_t)row * D_VIT + i] - bdec[i];

    float v[SLOTS];
#pragma unroll
    for (int i = 0; i < SLOTS; i++) v[i] = acts[(size_t)lrow * D_SAE + tid + 256 * i];

    unsigned long long dead = 0ull;
    for (int it = 0; it < NCAND; ++it) {
        float best = -1.0f; int bslot = 0;
#pragma unroll
        for (int i = 0; i < SLOTS; i++) {
            float xv = ((dead >> i) & 1ull) ? -1.0f : v[i];
            if (xv > best) { best = xv; bslot = i; }
        }
        unsigned int fb = best >= 0.0f ? __float_as_uint(best) : 0u;
        unsigned int fl = (unsigned int)(bslot * 256 + tid);
        unsigned long long p = ((unsigned long long)fb << 32) | (unsigned long long)(0xFFFFFFFFu - fl);
#pragma unroll
        for (int o = 1; o < 64; o <<= 1) {
            unsigned long long q = __shfl_xor(p, o);
            p = p > q ? p : q;
        }
        if ((tid & 63) == 0) red[tid >> 6] = p;
        __syncthreads();
        unsigned long long pm = red[0];
        if (red[1] > pm) pm = red[1];
        if (red[2] > pm) pm = red[2];
        if (red[3] > pm) pm = red[3];
        unsigned int f = 0xFFFFFFFFu - (unsigned int)(pm & 0xFFFFFFFFull);
        if (tid == (int)(f & 255u)) dead |= (1ull << (f >> 8));
        if (tid == 0) {
            cand_f[it] = (int)f;
            cval[it] = (double)__uint_as_float((unsigned int)(pm >> 32));
        }
        __syncthreads();
    }

    // exact f64 rerank of the 48 candidates
    {
        int c = tid >> 2, sub = tid & 3;
        double acc = 0.0;
        if (c < NCAND) {
            const float* wr = &wt[(size_t)cand_f[c] * D_VIT];
            for (int k = sub; k < D_VIT; k += 4)
                acc += (double)xs[k] * (double)wr[k];
        }
        acc += __shfl_xor(acc, 1);
        acc += __shfl_xor(acc, 2);
        if (c < NCAND && sub == 0) cval[c] = acc > 0.0 ? acc : 0.0;
        __syncthreads();
    }

    if (tid < 64) {
        double myv = tid < NCAND ? cval[tid] : -1.0;
        for (int it = 0; it < TOPK; ++it) {
            double m = myv;
#pragma unroll
            for (int o = 1; o < 64; o <<= 1) {
                double q = __shfl_xor(m, o);
                m = q > m ? q : m;
            }
            unsigned long long b = __ballot(myv == m);
            int src = __ffsll((unsigned long long)b) - 1;
            if (tid == src) myv = -1.0;
            if (tid == 0) { sidx[it] = cand_f[src]; sval[it] = (float)m; }
        }
    }
    __syncthreads();

    for (int d = tid; d < D_VIT; d += 256) {
        float o = bdec[d];
#pragma unroll
        for (int j = 0; j < TOPK; j++)
            o = fmaf(sval[j], wdec[(size_t)sidx[j] * D_VIT + d], o);
        out[(size_t)row * D_VIT + d] = o;
    }
}

extern "C" void kernel_launch(void* const* d_in, const int* in_sizes, int n_in,
                              void* d_out, int out_size, void* d_ws, size_t ws_size,
                              hipStream_t stream) {
    const float* x    = (const float*)d_in[0];
    const float* wenc = (const float*)d_in[1];
    const float* wdec = (const float*)d_in[2];
    const float* bdec = (const float*)d_in[3];
    float* out = (float*)d_out;
    int M = in_sizes[0] / D_VIT;

    size_t wt_b  = (size_t)D_SAE * D_VIT * sizeof(float);
    size_t wtb_b = (size_t)D_SAE * D_VIT * sizeof(__hip_bfloat16);
    size_t xb_b  = (size_t)M * D_VIT * sizeof(__hip_bfloat16);
    size_t fixed = wt_b + wtb_b + xb_b;
    size_t row_b = (size_t)D_SAE * sizeof(float);

    float* wt            = (float*)d_ws;
    __hip_bfloat16* wtb  = (__hip_bfloat16*)((char*)d_ws + wt_b);
    __hip_bfloat16* xb   = (__hip_bfloat16*)((char*)d_ws + wt_b + wtb_b);
    float* actbuf        = (float*)((char*)d_ws + fixed);

    long long chl = (long long)((ws_size > fixed ? ws_size - fixed : row_b) / row_b);
    int CH = (int)(chl < 1 ? 1 : (chl > (long long)M ? M : chl));
    if (CH >= 128) CH &= ~127;

    {
        dim3 g(D_SAE / 32, D_VIT / 32), b(32, 8);
        hipLaunchKernelGGL(k_transpose, g, b, 0, stream, wenc, wt, wtb);
    }
    {
        long long n = (long long)M * D_VIT;
        int blocks = (int)((n / 8 + 255) / 256);
        hipLaunchKernelGGL(k_cvt_x, dim3(blocks), dim3(256), 0, stream, x, bdec, xb, n);
    }
    for (int s = 0; s < M; s += CH) {
        int mr = (M - s) < CH ? (M - s) : CH;
        dim3 ge(D_SAE / EBN, (mr + EBM - 1) / EBM), be(256);
        hipLaunchKernelGGL(k_enc_mfma, ge, be, 0, stream, xb, wtb, actbuf, s, mr, M);
        hipLaunchKernelGGL(k_select, dim3(mr), dim3(256), 0, stream,
                           actbuf, x, bdec, wt, wdec, out, s, mr);
    }
}

// Round 3
// 1036.833 us; speedup vs baseline: 4.2048x; 2.0785x over previous
//
#include <hip/hip_runtime.h>
#include <hip/hip_bf16.h>
#include <stdint.h>

#define D_VIT 768
#define D_SAE 12288
#define TOPK 32
#define NC 48          // candidate target (superset of top-32)
#define HBINS 2048
#define CMAX 256

typedef __attribute__((ext_vector_type(8))) short bf8_t;   // 8 bf16 (4 VGPRs)
typedef __attribute__((ext_vector_type(4))) float f4_t;    // 4 f32 acc
typedef const __attribute__((address_space(1))) void* gas_t;
typedef __attribute__((address_space(3))) void* las_t;

// ---------------- transpose W_enc (768 x 12288) -> wt f32 + wtb bf16 ---------
__global__ void k_transpose(const float* __restrict__ src, float* __restrict__ dst,
                            __hip_bfloat16* __restrict__ dstb) {
    __shared__ float t[32][33];
    int f0 = blockIdx.x * 32, k0 = blockIdx.y * 32;
    int tx = threadIdx.x, ty = threadIdx.y;
#pragma unroll
    for (int j = 0; j < 32; j += 8)
        t[ty + j][tx] = src[(size_t)(k0 + ty + j) * D_SAE + f0 + tx];
    __syncthreads();
#pragma unroll
    for (int j = 0; j < 32; j += 8) {
        float v = t[tx][ty + j];
        dst[(size_t)(f0 + ty + j) * D_VIT + k0 + tx] = v;
        dstb[(size_t)(f0 + ty + j) * D_VIT + k0 + tx] = __float2bfloat16(v);
    }
}

// ---------------- xb = bf16(x - b_dec) ---------------------------------------
__global__ __launch_bounds__(256) void k_cvt_x(const float* __restrict__ x,
    const float* __restrict__ bdec, __hip_bfloat16* __restrict__ xb, long long n) {
    long long i = ((long long)blockIdx.x * 256 + threadIdx.x) * 8;
    if (i >= n) return;
    float4 a = *reinterpret_cast<const float4*>(x + i);
    float4 b = *reinterpret_cast<const float4*>(x + i + 4);
    int kk = (int)(i % D_VIT);
    float4 c = *reinterpret_cast<const float4*>(bdec + kk);
    float4 d = *reinterpret_cast<const float4*>(bdec + kk + 4);
    union { __hip_bfloat16 h[8]; uint4 v; } o;
    o.h[0] = __float2bfloat16(a.x - c.x); o.h[1] = __float2bfloat16(a.y - c.y);
    o.h[2] = __float2bfloat16(a.z - c.z); o.h[3] = __float2bfloat16(a.w - c.w);
    o.h[4] = __float2bfloat16(b.x - d.x); o.h[5] = __float2bfloat16(b.y - d.y);
    o.h[6] = __float2bfloat16(b.z - d.z); o.h[7] = __float2bfloat16(b.w - d.w);
    *reinterpret_cast<uint4*>(xb + i) = o.v;
}

// ---------------- MFMA encoder: actsb = bf16(relu(xb @ wtb^T)) ---------------
#define EBM 128
#define EBN 128
#define EBK 64

__global__ __launch_bounds__(256) void k_enc_mfma(
    const __hip_bfloat16* __restrict__ xb, const __hip_bfloat16* __restrict__ wtb,
    __hip_bfloat16* __restrict__ actsb, int row0, int mrows, int Mtot) {
    __shared__ __hip_bfloat16 As[EBM * EBK];
    __shared__ __hip_bfloat16 Bs[EBN * EBK];
    int tid = threadIdx.x;
    int lane = tid & 63, w = tid >> 6;
    int wm = w >> 1, wn = w & 1;
    int tile_m = blockIdx.y * EBM, tile_n = blockIdx.x * EBN;

    f4_t acc[4][4] = {};

#pragma unroll 1
    for (int k0 = 0; k0 < D_VIT; k0 += EBK) {
#pragma unroll
        for (int j = 0; j < 4; ++j) {
            int G = w * 64 + j * 256 + lane;
            int r = G >> 3, g = G & 7;
            int gg = g ^ (r & 7);
            int ar = row0 + tile_m + r; if (ar >= Mtot) ar = Mtot - 1;
            const __hip_bfloat16* ga = xb + (size_t)ar * D_VIT + k0 + gg * 8;
            __builtin_amdgcn_global_load_lds((gas_t)ga,
                (las_t)(As + (w * 64 + j * 256) * 8), 16, 0, 0);
            const __hip_bfloat16* gb = wtb + (size_t)(tile_n + r) * D_VIT + k0 + gg * 8;
            __builtin_amdgcn_global_load_lds((gas_t)gb,
                (las_t)(Bs + (w * 64 + j * 256) * 8), 16, 0, 0);
        }
        __syncthreads();

        int lrow = lane & 15, lk = lane >> 4;
#pragma unroll
        for (int half = 0; half < 2; ++half) {
            int g = lk + half * 4;
            bf8_t af[4], bfr[4];
#pragma unroll
            for (int f = 0; f < 4; ++f) {
                int r = wm * 64 + f * 16 + lrow;
                af[f] = *reinterpret_cast<const bf8_t*>(As + r * EBK + ((g ^ (lrow & 7)) << 3));
                int rn = wn * 64 + f * 16 + lrow;
                bfr[f] = *reinterpret_cast<const bf8_t*>(Bs + rn * EBK + ((g ^ (lrow & 7)) << 3));
            }
#pragma unroll
            for (int i = 0; i < 4; ++i)
#pragma unroll
                for (int jn = 0; jn < 4; ++jn)
                    acc[i][jn] = __builtin_amdgcn_mfma_f32_16x16x32_bf16(
                        af[i], bfr[jn], acc[i][jn], 0, 0, 0);
        }
        __syncthreads();
    }

#pragma unroll
    for (int i = 0; i < 4; ++i) {
        int rbase = tile_m + wm * 64 + i * 16 + (lane >> 4) * 4;
#pragma unroll
        for (int jn = 0; jn < 4; ++jn) {
            int c = tile_n + wn * 64 + jn * 16 + (lane & 15);
#pragma unroll
            for (int q = 0; q < 4; ++q) {
                int rr = rbase + q;
                if (rr < mrows)
                    actsb[(size_t)rr * D_SAE + c] = __float2bfloat16(fmaxf(acc[i][jn][q], 0.f));
            }
        }
    }
}

// -------- per-row: histogram top-48 superset, f64 rerank, rank<32, decode ----
__global__ __launch_bounds__(256) void k_select(
    const __hip_bfloat16* __restrict__ actsb, const float* __restrict__ x,
    const float* __restrict__ bdec, const float* __restrict__ wt,
    const float* __restrict__ wdec, float* __restrict__ out,
    int row0, int mrows) {
    int lrow = blockIdx.x;
    int row = row0 + lrow;
    int tid = threadIdx.x;

    __shared__ float xs[D_VIT];
    __shared__ unsigned int hist[HBINS];
    __shared__ unsigned int seg[256];
    __shared__ int cand[CMAX];
    __shared__ double cval[CMAX];
    __shared__ float sval[TOPK];
    __shared__ int sidx[TOPK];
    __shared__ int s_cnt, s_bstar;

#pragma unroll
    for (int i = 0; i < HBINS / 256; ++i) hist[tid + 256 * i] = 0;
    if (tid == 0) { s_cnt = 0; s_bstar = 0; }
    for (int i = tid; i < D_VIT; i += 256) xs[i] = x[(size_t)row * D_VIT + i] - bdec[i];

    // 48 bf16 acts per thread, coalesced 16B loads
    uint4 u[6];
    const uint4* arow = reinterpret_cast<const uint4*>(actsb + (size_t)lrow * D_SAE);
#pragma unroll
    for (int j = 0; j < 6; ++j) u[j] = arow[256 * j + tid];
    __syncthreads();

    // histogram of positive bf16 bit-patterns (monotonic), zeros skipped
#pragma unroll
    for (int j = 0; j < 6; ++j) {
        unsigned int ww[4] = { u[j].x, u[j].y, u[j].z, u[j].w };
#pragma unroll
        for (int p = 0; p < 4; ++p) {
            unsigned int h0 = ww[p] & 0xffffu, h1 = ww[p] >> 16;
            if (h0 && h0 < 0x8000u) atomicAdd(&hist[h0 >> 5], 1u);
            if (h1 && h1 < 0x8000u) atomicAdd(&hist[h1 >> 5], 1u);
        }
    }
    __syncthreads();

    // segment sums (8 bins/thread) then Hillis-Steele suffix scan
    unsigned int ss = 0;
#pragma unroll
    for (int b = 0; b < 8; ++b) ss += hist[tid * 8 + b];
    seg[tid] = ss;
    __syncthreads();
    for (int d = 1; d < 256; d <<= 1) {
        unsigned int t2 = (tid + d < 256) ? seg[tid + d] : 0u;
        __syncthreads();
        seg[tid] += t2;
        __syncthreads();
    }
    // threshold bin b*: largest bin with count_ge(bin) >= NC
    if (seg[tid] >= NC && (tid == 255 || seg[tid + 1] < NC)) {
        unsigned int run = (tid == 255) ? 0u : seg[tid + 1];
        int bs = tid * 8;
        for (int b = tid * 8 + 7; b >= tid * 8; --b) {
            run += hist[b];
            if (run >= NC) { bs = b; break; }
        }
        s_bstar = bs;
    }
    __syncthreads();
    int bstar = s_bstar;  // 0 if fewer than NC positives -> all positives

    // compact candidate indices
#pragma unroll
    for (int j = 0; j < 6; ++j) {
        unsigned int ww[4] = { u[j].x, u[j].y, u[j].z, u[j].w };
#pragma unroll
        for (int p = 0; p < 4; ++p) {
            unsigned int h0 = ww[p] & 0xffffu, h1 = ww[p] >> 16;
            if (h0 && h0 < 0x8000u && (int)(h0 >> 5) >= bstar) {
                int slot = atomicAdd(&s_cnt, 1);
                if (slot < CMAX) cand[slot] = j * 2048 + tid * 8 + p * 2;
            }
            if (h1 && h1 < 0x8000u && (int)(h1 >> 5) >= bstar) {
                int slot = atomicAdd(&s_cnt, 1);
                if (slot < CMAX) cand[slot] = j * 2048 + tid * 8 + p * 2 + 1;
            }
        }
    }
    __syncthreads();
    int C = s_cnt < CMAX ? s_cnt : CMAX;

    // exact f64 rerank: 4 threads per candidate
    for (int base = 0; base < C; base += 64) {
        int c = base + (tid >> 2), sub = tid & 3;
        if (c < C) {
            const float* wr = wt + (size_t)cand[c] * D_VIT;
            double acc = 0.0;
            for (int k = sub * 4; k < D_VIT; k += 16) {
                float4 wv = *reinterpret_cast<const float4*>(wr + k);
                float4 xv = *reinterpret_cast<const float4*>(xs + k);
                acc += (double)wv.x * xv.x + (double)wv.y * xv.y
                     + (double)wv.z * xv.z + (double)wv.w * xv.w;
            }
            acc += __shfl_xor(acc, 1);
            acc += __shfl_xor(acc, 2);
            if (sub == 0) cval[c] = acc > 0.0 ? acc : 0.0;
        }
    }
    if (tid < TOPK) { sval[tid] = 0.f; sidx[tid] = 0; }
    __syncthreads();

    // parallel rank (order-independent top-32 routing)
    if (tid < C) {
        double mv = cval[tid]; int mi = cand[tid];
        int rank = 0;
        for (int j = 0; j < C; ++j) {
            double vj = cval[j];
            rank += (vj > mv) || (vj == mv && cand[j] < mi);
        }
        if (rank < TOPK) { sval[rank] = (float)mv; sidx[rank] = mi; }
    }
    __syncthreads();

    // sparse decode + b_dec
    for (int d = tid; d < D_VIT; d += 256) {
        float o = bdec[d];
#pragma unroll
        for (int j = 0; j < TOPK; j++)
            o = fmaf(sval[j], wdec[(size_t)sidx[j] * D_VIT + d], o);
        out[(size_t)row * D_VIT + d] = o;
    }
}

extern "C" void kernel_launch(void* const* d_in, const int* in_sizes, int n_in,
                              void* d_out, int out_size, void* d_ws, size_t ws_size,
                              hipStream_t stream) {
    const float* x    = (const float*)d_in[0];
    const float* wenc = (const float*)d_in[1];
    const float* wdec = (const float*)d_in[2];
    const float* bdec = (const float*)d_in[3];
    float* out = (float*)d_out;
    int M = in_sizes[0] / D_VIT;

    size_t wt_b  = (size_t)D_SAE * D_VIT * sizeof(float);
    size_t wtb_b = (size_t)D_SAE * D_VIT * sizeof(__hip_bfloat16);
    size_t xb_b  = (size_t)M * D_VIT * sizeof(__hip_bfloat16);
    size_t fixed = wt_b + wtb_b + xb_b;
    size_t row_b = (size_t)D_SAE * sizeof(__hip_bfloat16);

    float* wt            = (float*)d_ws;
    __hip_bfloat16* wtb  = (__hip_bfloat16*)((char*)d_ws + wt_b);
    __hip_bfloat16* xb   = (__hip_bfloat16*)((char*)d_ws + wt_b + wtb_b);
    __hip_bfloat16* actb = (__hip_bfloat16*)((char*)d_ws + fixed);

    long long chl = (long long)((ws_size > fixed ? ws_size - fixed : row_b) / row_b);
    int CH = (int)(chl < 1 ? 1 : (chl > (long long)M ? M : chl));
    if (CH >= 128 && CH < M) CH &= ~127;

    {
        dim3 g(D_SAE / 32, D_VIT / 32), b(32, 8);
        hipLaunchKernelGGL(k_transpose, g, b, 0, stream, wenc, wt, wtb);
    }
    {
        long long n = (long long)M * D_VIT;
        int blocks = (int)((n / 8 + 255) / 256);
        hipLaunchKernelGGL(k_cvt_x, dim3(blocks), dim3(256), 0, stream, x, bdec, xb, n);
    }
    for (int s = 0; s < M; s += CH) {
        int mr = (M - s) < CH ? (M - s) : CH;
        dim3 ge(D_SAE / EBN, (mr + EBM - 1) / EBM), be(256);
        hipLaunchKernelGGL(k_enc_mfma, ge, be, 0, stream, xb, wtb, actb, s, mr, M);
        hipLaunchKernelGGL(k_select, dim3(mr), dim3(256), 0, stream,
                           actb, x, bdec, wt, wdec, out, s, mr);
    }
}

// Round 4
// 872.055 us; speedup vs baseline: 4.9993x; 1.1890x over previous
//
#include <hip/hip_runtime.h>
#include <hip/hip_bf16.h>
#include <stdint.h>

#define D_VIT 768
#define D_SAE 12288
#define TOPK 32
#define NC 48          // candidate superset target
#define CMAX 128

typedef __attribute__((ext_vector_type(8))) short bf8_t;   // 8 bf16 (4 VGPRs)
typedef __attribute__((ext_vector_type(4))) float f4_t;    // 4 f32 acc
typedef const __attribute__((address_space(1))) void* gas_t;
typedef __attribute__((address_space(3))) void* las_t;

// ---------------- transpose W_enc (768 x 12288) -> wt f32 + wtb bf16 ---------
__global__ void k_transpose(const float* __restrict__ src, float* __restrict__ dst,
                            __hip_bfloat16* __restrict__ dstb) {
    __shared__ float t[32][33];
    int f0 = blockIdx.x * 32, k0 = blockIdx.y * 32;
    int tx = threadIdx.x, ty = threadIdx.y;
#pragma unroll
    for (int j = 0; j < 32; j += 8)
        t[ty + j][tx] = src[(size_t)(k0 + ty + j) * D_SAE + f0 + tx];
    __syncthreads();
#pragma unroll
    for (int j = 0; j < 32; j += 8) {
        float v = t[tx][ty + j];
        dst[(size_t)(f0 + ty + j) * D_VIT + k0 + tx] = v;
        dstb[(size_t)(f0 + ty + j) * D_VIT + k0 + tx] = __float2bfloat16(v);
    }
}

// ---------------- xb = bf16(x - b_dec) ---------------------------------------
__global__ __launch_bounds__(256) void k_cvt_x(const float* __restrict__ x,
    const float* __restrict__ bdec, __hip_bfloat16* __restrict__ xb, long long n) {
    long long i = ((long long)blockIdx.x * 256 + threadIdx.x) * 8;
    if (i >= n) return;
    float4 a = *reinterpret_cast<const float4*>(x + i);
    float4 b = *reinterpret_cast<const float4*>(x + i + 4);
    int kk = (int)(i % D_VIT);
    float4 c = *reinterpret_cast<const float4*>(bdec + kk);
    float4 d = *reinterpret_cast<const float4*>(bdec + kk + 4);
    union { __hip_bfloat16 h[8]; uint4 v; } o;
    o.h[0] = __float2bfloat16(a.x - c.x); o.h[1] = __float2bfloat16(a.y - c.y);
    o.h[2] = __float2bfloat16(a.z - c.z); o.h[3] = __float2bfloat16(a.w - c.w);
    o.h[4] = __float2bfloat16(b.x - d.x); o.h[5] = __float2bfloat16(b.y - d.y);
    o.h[6] = __float2bfloat16(b.z - d.z); o.h[7] = __float2bfloat16(b.w - d.w);
    *reinterpret_cast<uint4*>(xb + i) = o.v;
}

// ---------------- MFMA encoder: actsb = bf16(relu(xb @ wtb^T)) ---------------
// Swapped operands: D[feature][xrow] so lane's 4 acc regs = 4 consecutive
// features of one x-row -> packed 8B stores.
#define EBM 128
#define EBN 128
#define EBK 64

__global__ __launch_bounds__(256) void k_enc_mfma(
    const __hip_bfloat16* __restrict__ xb, const __hip_bfloat16* __restrict__ wtb,
    __hip_bfloat16* __restrict__ actsb, int row0, int mrows, int Mtot) {
    __shared__ __hip_bfloat16 As[EBM * EBK];
    __shared__ __hip_bfloat16 Bs[EBN * EBK];
    int tid = threadIdx.x;
    int lane = tid & 63, w = tid >> 6;
    int wm = w >> 1, wn = w & 1;
    int tile_m = blockIdx.y * EBM, tile_n = blockIdx.x * EBN;

    f4_t acc[4][4] = {};

#pragma unroll 1
    for (int k0 = 0; k0 < D_VIT; k0 += EBK) {
#pragma unroll
        for (int j = 0; j < 4; ++j) {
            int G = w * 64 + j * 256 + lane;
            int r = G >> 3, g = G & 7;
            int gg = g ^ (r & 7);
            int ar = row0 + tile_m + r; if (ar >= Mtot) ar = Mtot - 1;
            const __hip_bfloat16* ga = xb + (size_t)ar * D_VIT + k0 + gg * 8;
            __builtin_amdgcn_global_load_lds((gas_t)ga,
                (las_t)(As + (w * 64 + j * 256) * 8), 16, 0, 0);
            const __hip_bfloat16* gb = wtb + (size_t)(tile_n + r) * D_VIT + k0 + gg * 8;
            __builtin_amdgcn_global_load_lds((gas_t)gb,
                (las_t)(Bs + (w * 64 + j * 256) * 8), 16, 0, 0);
        }
        __syncthreads();

        int lrow = lane & 15, lk = lane >> 4;
#pragma unroll
        for (int half = 0; half < 2; ++half) {
            int g = lk + half * 4;
            bf8_t af[4], bfr[4];
#pragma unroll
            for (int f = 0; f < 4; ++f) {
                int r = wm * 64 + f * 16 + lrow;
                af[f] = *reinterpret_cast<const bf8_t*>(As + r * EBK + ((g ^ (lrow & 7)) << 3));
                int rn = wn * 64 + f * 16 + lrow;
                bfr[f] = *reinterpret_cast<const bf8_t*>(Bs + rn * EBK + ((g ^ (lrow & 7)) << 3));
            }
#pragma unroll
            for (int i = 0; i < 4; ++i)
#pragma unroll
                for (int jn = 0; jn < 4; ++jn)
                    acc[i][jn] = __builtin_amdgcn_mfma_f32_16x16x32_bf16(
                        bfr[jn], af[i], acc[i][jn], 0, 0, 0);
        }
        __syncthreads();
    }

    // D[feature][xrow]: feature = (lane>>4)*4 + q (within 16), xrow = lane&15
#pragma unroll
    for (int i = 0; i < 4; ++i) {
        int xr = tile_m + wm * 64 + i * 16 + (lane & 15);
        if (xr < mrows) {
            __hip_bfloat16* rowp = actsb + (size_t)xr * D_SAE;
#pragma unroll
            for (int jn = 0; jn < 4; ++jn) {
                int fb = tile_n + wn * 64 + jn * 16 + ((lane >> 4) << 2);
                union { __hip_bfloat16 h[4]; uint2 u; } o;
                o.h[0] = __float2bfloat16(fmaxf(acc[i][jn][0], 0.f));
                o.h[1] = __float2bfloat16(fmaxf(acc[i][jn][1], 0.f));
                o.h[2] = __float2bfloat16(fmaxf(acc[i][jn][2], 0.f));
                o.h[3] = __float2bfloat16(fmaxf(acc[i][jn][3], 0.f));
                *reinterpret_cast<uint2*>(rowp + fb) = o.u;
            }
        }
    }
}

// -------- per-row: two-level exact-code threshold, f64 rerank, rank, decode --
__global__ __launch_bounds__(256) void k_select(
    const __hip_bfloat16* __restrict__ actsb, const float* __restrict__ x,
    const float* __restrict__ bdec, const float* __restrict__ wt,
    const float* __restrict__ wdec, float* __restrict__ out,
    int row0, int mrows) {
    int lrow = blockIdx.x;
    int row = row0 + lrow;
    int tid = threadIdx.x;

    __shared__ float xs[D_VIT];
    __shared__ unsigned int hist1[256];
    __shared__ unsigned int hist2[128];
    __shared__ int cand[CMAX];
    __shared__ double cval[CMAX];
    __shared__ float sval[TOPK];
    __shared__ int sidx[TOPK];
    __shared__ int s_cnt, s_b1, s_code;
    __shared__ unsigned int s_above;

    hist1[tid] = 0;
    if (tid < 128) hist2[tid] = 0;
    if (tid < TOPK) { sval[tid] = 0.f; sidx[tid] = 0; }
    if (tid == 0) { s_cnt = 0; s_b1 = -1; s_code = 1; s_above = 0; }
    for (int i = tid; i < D_VIT; i += 256) xs[i] = x[(size_t)row * D_VIT + i] - bdec[i];

    uint4 u[6];
    const uint4* arow = reinterpret_cast<const uint4*>(actsb + (size_t)lrow * D_SAE);
#pragma unroll
    for (int j = 0; j < 6; ++j) u[j] = arow[256 * j + tid];
    __syncthreads();

    // level-1 histogram: 256 bins over code>>7 (positives only)
#pragma unroll
    for (int j = 0; j < 6; ++j) {
        unsigned int ww[4] = { u[j].x, u[j].y, u[j].z, u[j].w };
#pragma unroll
        for (int p = 0; p < 4; ++p) {
            unsigned int h0 = ww[p] & 0xffffu, h1 = ww[p] >> 16;
            if (h0 && h0 < 0x8000u) atomicAdd(&hist1[h0 >> 7], 1u);
            if (h1 && h1 < 0x8000u) atomicAdd(&hist1[h1 >> 7], 1u);
        }
    }
    __syncthreads();

    // wave-0 suffix scan over 256 bins (4 per lane)
    if (tid < 64) {
        int l = tid;
        unsigned c0 = hist1[4 * l], c1 = hist1[4 * l + 1],
                 c2 = hist1[4 * l + 2], c3 = hist1[4 * l + 3];
        unsigned S = c0 + c1 + c2 + c3;
#pragma unroll
        for (int o = 1; o < 64; o <<= 1) {
            unsigned t = __shfl_down(S, o);
            if (l + o < 64) S += t;
        }
        unsigned above = __shfl_down(S, 1);
        if (l == 63) above = 0;
        if (S >= NC && above < NC) {
            int b1; unsigned ab;
            if (above + c3 >= NC)                 { b1 = 4 * l + 3; ab = above; }
            else if (above + c3 + c2 >= NC)       { b1 = 4 * l + 2; ab = above + c3; }
            else if (above + c3 + c2 + c1 >= NC)  { b1 = 4 * l + 1; ab = above + c3 + c2; }
            else                                  { b1 = 4 * l;     ab = above + c3 + c2 + c1; }
            s_b1 = b1; s_above = ab;
        }
    }
    __syncthreads();
    int b1 = s_b1;

    if (b1 >= 0) {
        // level-2 histogram: 128 sub-codes within bin b1
#pragma unroll
        for (int j = 0; j < 6; ++j) {
            unsigned int ww[4] = { u[j].x, u[j].y, u[j].z, u[j].w };
#pragma unroll
            for (int p = 0; p < 4; ++p) {
                unsigned int h0 = ww[p] & 0xffffu, h1 = ww[p] >> 16;
                if (h0 && h0 < 0x8000u && (int)(h0 >> 7) == b1) atomicAdd(&hist2[h0 & 127u], 1u);
                if (h1 && h1 < 0x8000u && (int)(h1 >> 7) == b1) atomicAdd(&hist2[h1 & 127u], 1u);
            }
        }
        __syncthreads();
        if (tid < 64) {
            int l = tid;
            unsigned above0 = s_above;
            unsigned c0 = hist2[2 * l], c1 = hist2[2 * l + 1];
            unsigned S = c0 + c1;
#pragma unroll
            for (int o = 1; o < 64; o <<= 1) {
                unsigned t = __shfl_down(S, o);
                if (l + o < 64) S += t;
            }
            unsigned ab2 = __shfl_down(S, 1);
            if (l == 63) ab2 = 0;
            if (above0 + S >= NC && above0 + ab2 < NC) {
                if (above0 + ab2 + c1 >= NC) s_code = (b1 << 7) | (2 * l + 1);
                else                         s_code = (b1 << 7) | (2 * l);
            }
        }
        __syncthreads();
    }
    int code = s_code;

    // compact candidates: all positives with code >= threshold
#pragma unroll
    for (int j = 0; j < 6; ++j) {
        unsigned int ww[4] = { u[j].x, u[j].y, u[j].z, u[j].w };
#pragma unroll
        for (int p = 0; p < 4; ++p) {
            unsigned int h0 = ww[p] & 0xffffu, h1 = ww[p] >> 16;
            if (h0 < 0x8000u && (int)h0 >= code) {
                int slot = atomicAdd(&s_cnt, 1);
                if (slot < CMAX) cand[slot] = j * 2048 + tid * 8 + p * 2;
            }
            if (h1 < 0x8000u && (int)h1 >= code) {
                int slot = atomicAdd(&s_cnt, 1);
                if (slot < CMAX) cand[slot] = j * 2048 + tid * 8 + p * 2 + 1;
            }
        }
    }
    __syncthreads();
    int C = s_cnt < CMAX ? s_cnt : CMAX;

    // exact f64 rerank: 4 threads per candidate
    for (int base = 0; base < C; base += 64) {
        int c = base + (tid >> 2), sub = tid & 3;
        if (c < C) {
            const float* wr = wt + (size_t)cand[c] * D_VIT;
            double acc = 0.0;
            for (int k = sub * 4; k < D_VIT; k += 16) {
                float4 wv = *reinterpret_cast<const float4*>(wr + k);
                float4 xv = *reinterpret_cast<const float4*>(xs + k);
                acc += (double)wv.x * xv.x + (double)wv.y * xv.y
                     + (double)wv.z * xv.z + (double)wv.w * xv.w;
            }
            acc += __shfl_xor(acc, 1);
            acc += __shfl_xor(acc, 2);
            if (sub == 0) cval[c] = acc > 0.0 ? acc : 0.0;
        }
    }
    __syncthreads();

    // parallel rank-routing (deterministic regardless of cand order)
    if (tid < C) {
        double mv = cval[tid]; int mi = cand[tid];
        int rank = 0;
        for (int j = 0; j < C; ++j) {
            double vj = cval[j];
            rank += (vj > mv) || (vj == mv && cand[j] < mi);
        }
        if (rank < TOPK) { sval[rank] = (float)mv; sidx[rank] = mi; }
    }
    __syncthreads();

    // sparse decode + b_dec
    for (int d = tid; d < D_VIT; d += 256) {
        float o = bdec[d];
#pragma unroll
        for (int j = 0; j < TOPK; j++)
            o = fmaf(sval[j], wdec[(size_t)sidx[j] * D_VIT + d], o);
        out[(size_t)row * D_VIT + d] = o;
    }
}

extern "C" void kernel_launch(void* const* d_in, const int* in_sizes, int n_in,
                              void* d_out, int out_size, void* d_ws, size_t ws_size,
                              hipStream_t stream) {
    const float* x    = (const float*)d_in[0];
    const float* wenc = (const float*)d_in[1];
    const float* wdec = (const float*)d_in[2];
    const float* bdec = (const float*)d_in[3];
    float* out = (float*)d_out;
    int M = in_sizes[0] / D_VIT;

    size_t wt_b  = (size_t)D_SAE * D_VIT * sizeof(float);
    size_t wtb_b = (size_t)D_SAE * D_VIT * sizeof(__hip_bfloat16);
    size_t xb_b  = (size_t)M * D_VIT * sizeof(__hip_bfloat16);
    size_t fixed = wt_b + wtb_b + xb_b;
    size_t row_b = (size_t)D_SAE * sizeof(__hip_bfloat16);

    float* wt            = (float*)d_ws;
    __hip_bfloat16* wtb  = (__hip_bfloat16*)((char*)d_ws + wt_b);
    __hip_bfloat16* xb   = (__hip_bfloat16*)((char*)d_ws + wt_b + wtb_b);
    __hip_bfloat16* actb = (__hip_bfloat16*)((char*)d_ws + fixed);

    long long chl = (long long)((ws_size > fixed ? ws_size - fixed : row_b) / row_b);
    int CH = (int)(chl < 1 ? 1 : (chl > (long long)M ? M : chl));
    if (CH >= 128 && CH < M) CH &= ~127;

    {
        dim3 g(D_SAE / 32, D_VIT / 32), b(32, 8);
        hipLaunchKernelGGL(k_transpose, g, b, 0, stream, wenc, wt, wtb);
    }
    {
        long long n = (long long)M * D_VIT;
        int blocks = (int)((n / 8 + 255) / 256);
        hipLaunchKernelGGL(k_cvt_x, dim3(blocks), dim3(256), 0, stream, x, bdec, xb, n);
    }
    for (int s = 0; s < M; s += CH) {
        int mr = (M - s) < CH ? (M - s) : CH;
        dim3 ge(D_SAE / EBN, (mr + EBM - 1) / EBM), be(256);
        hipLaunchKernelGGL(k_enc_mfma, ge, be, 0, stream, xb, wtb, actb, s, mr, M);
        hipLaunchKernelGGL(k_select, dim3(mr), dim3(256), 0, stream,
                           actb, x, bdec, wt, wdec, out, s, mr);
    }
}